// Round 7
// baseline (97.634 us; speedup 1.0000x reference)
//
#include <hip/hip_runtime.h>

// y[32,8192] = x[32,8192] @ (A[8192,64] @ B[64,8192])^T + bias
// Factored: t = x @ B^T [32,64]; y = t @ A^T + bias.
// Two kernels (round-2 structure — measured best; software grid barriers and
// cg::sync both cost MORE than the HW kernel-boundary drain on gfx950).
// k1: split-K partials part[128][32][64] (1 MB ws), no atomics/memset.
// k2: per-block reduce + A^T apply. og = bid&31 so the 8 blocks sharing an
//     A-tile land on the SAME XCD under bid%8 round-robin -> A L2-shared,
//     not re-fetched 8x from HBM. A kept in registers (VGPR=68, 7 waves/SIMD).

#define BATCH 32
#define RANK  64
#define OUTF  8192
#define KCH   128            // k1 blocks; chunk = 64 floats = 16 float4

// ---------------- k1: part[c][32][64] = x[:,chunk_c] @ B[:,chunk_c]^T ----------
__global__ __launch_bounds__(256) void lr_k1(const float* __restrict__ x,
                                             const float* __restrict__ B,
                                             float* __restrict__ part) {
    const int c   = blockIdx.x;
    const int tid = threadIdx.x;

    __shared__ float4 xs[BATCH * 16];  // row-major, kk XOR-swizzled
    __shared__ float4 bs[RANK * 16];

    const float4* x4 = (const float4*)x;  // row stride 2048 f4
    const float4* b4 = (const float4*)B;

#pragma unroll
    for (int it = 0; it < 2; ++it) {
        int gi = tid + it * 256, row = gi >> 4, kk = gi & 15;
        xs[row * 16 + (kk ^ (row & 15))] = x4[row * 2048 + c * 16 + kk];
    }
#pragma unroll
    for (int it = 0; it < 4; ++it) {
        int gi = tid + it * 256, row = gi >> 4, kk = gi & 15;
        bs[row * 16 + (kk ^ (row & 15))] = b4[row * 2048 + c * 16 + kk];
    }
    __syncthreads();

    // Thread tile: 2 batches x 4 ranks, ranks strided by 16 (keeps compute-phase
    // LDS reads at <=2-way aliasing: 16 distinct (r&15) values across 16 lanes).
    const int bq = tid >> 4;   // b rows: bq*2, bq*2+1
    const int rr = tid & 15;   // r cols: rr + 16j

    float acc[2][4] = {};
#pragma unroll
    for (int kk = 0; kk < 16; ++kk) {
        float4 xa[2], bb[4];
#pragma unroll
        for (int i = 0; i < 2; ++i) {
            int row = bq * 2 + i;
            xa[i] = xs[row * 16 + (kk ^ (row & 15))];   // 4 rows/wave -> broadcast
        }
#pragma unroll
        for (int j = 0; j < 4; ++j) {
            int r = rr + 16 * j;
            bb[j] = bs[r * 16 + (kk ^ (r & 15))];       // 2-way -> free (m136)
        }
#pragma unroll
        for (int i = 0; i < 2; ++i)
#pragma unroll
            for (int j = 0; j < 4; ++j)
                acc[i][j] += xa[i].x * bb[j].x + xa[i].y * bb[j].y +
                             xa[i].z * bb[j].z + xa[i].w * bb[j].w;
    }

    // part[c][b][r]: 16 consecutive lanes -> 64B contiguous stores (fire-and-forget)
#pragma unroll
    for (int i = 0; i < 2; ++i)
#pragma unroll
        for (int j = 0; j < 4; ++j)
            part[c * 2048 + (bq * 2 + i) * 64 + 16 * j + rr] = acc[i][j];
}

// ---------------- k2: y = reduce(part) @ A^T + bias ----------------
__global__ __launch_bounds__(256) void lr_k2(const float* __restrict__ A,
                                             const float* __restrict__ part,
                                             const float* __restrict__ bias,
                                             float* __restrict__ y) {
    const int bid = blockIdx.x;
    const int tid = threadIdx.x;
    const int og  = bid & 31;            // blocks sharing og: bids og+32k -> same
    const int b0  = (bid >> 5) * 4;      // XCD under bid%8 round-robin (A L2-shared)
    const int o   = og * 256 + tid;

    __shared__ float ts[4 * RANK];       // reduced t rows b0..b0+3

    // A row into registers; loads are in flight while the reduce below runs.
    const float4* A4 = (const float4*)A;   // A[o][r] -> A4[o*16 + r4]
    float4 areg[16];
#pragma unroll
    for (int r4 = 0; r4 < 16; ++r4) areg[r4] = A4[o * 16 + r4];
    const float bv = bias[o];

    // Reduce partials: element tid of the 4x64 slice, over 128 chunks.
    // Per-c: 256 lanes read 1 KB contiguous (coalesced, L2/L3-resident).
    {
        float s = 0.f;
#pragma unroll 16
        for (int c = 0; c < KCH; ++c) s += part[c * 2048 + b0 * 64 + tid];
        ts[tid] = s;
    }
    __syncthreads();

    float accv[4] = {bv, bv, bv, bv};
    const float4* t4 = (const float4*)ts;
#pragma unroll
    for (int r4 = 0; r4 < 16; ++r4) {
        float4 a = areg[r4];
#pragma unroll
        for (int jb = 0; jb < 4; ++jb) {
            float4 tv = t4[jb * 16 + r4];   // wave-uniform -> LDS broadcast, free
            accv[jb] += a.x * tv.x + a.y * tv.y + a.z * tv.z + a.w * tv.w;
        }
    }
#pragma unroll
    for (int jb = 0; jb < 4; ++jb)
        y[(b0 + jb) * OUTF + o] = accv[jb];   // coalesced
}

extern "C" void kernel_launch(void* const* d_in, const int* in_sizes, int n_in,
                              void* d_out, int out_size, void* d_ws, size_t ws_size,
                              hipStream_t stream) {
    const float* x    = (const float*)d_in[0];   // [32, 8192]
    const float* A    = (const float*)d_in[1];   // [8192, 64]
    const float* B    = (const float*)d_in[2];   // [64, 8192]
    const float* bias = (const float*)d_in[3];   // [8192]
    float*       y    = (float*)d_out;           // [32, 8192]
    float*       part = (float*)d_ws;            // [128][32][64] partials (1 MB)

    lr_k1<<<KCH, 256, 0, stream>>>(x, B, part);
    lr_k2<<<256, 256, 0, stream>>>(A, part, bias, y);
}